// Round 10
// baseline (373.080 us; speedup 1.0000x reference)
//
#include <hip/hip_runtime.h>
#include <hip/hip_bf16.h>
#include <cstdint>

#define S_LEN 4096
#define D_DIM 512
#define NWIN  511
#define KDIM  8192
#define TR3   1032                // 8*128+8 x-rows per union A-tile (BM=128)
#define ROWB  72                  // padded row bytes (32 bf16 = 64 B data + 8 pad)

typedef __attribute__((ext_vector_type(8))) short short8;
typedef __attribute__((ext_vector_type(4))) short short4v;
typedef __attribute__((ext_vector_type(4))) float f32x4;

__device__ __forceinline__ unsigned short f2b(float f) {
    union { float f; unsigned int u; } v; v.f = f;
    unsigned int r = v.u + 0x7FFFu + ((v.u >> 16) & 1u);
    return (unsigned short)(r >> 16);
}

// ---------------------------------------------------------------------------
// Pre-pass (verified R8/R9): W [8192][512] fp32 -> bf16 fragments, K=32
// slice-major. q2 = (c0*2+k32)*16 + t. Fragment content:
//   value = W[t*512 + c0*64 + k32*32 + hi*8 + e][64*w + 16*n + r15]
//   at short8 offset q2*2048 + w*256 + n*64 + lane.
// ---------------------------------------------------------------------------
__global__ void wpack2_kernel(const float* __restrict__ W, short8* __restrict__ pk) {
    __shared__ float tile[64][68];
    const int b2 = blockIdx.x;           // (t*8+c0)*8 + w
    const int s = b2 >> 3, w = b2 & 7;
    const int t = s >> 3, c0 = s & 7;
    const int tid = threadIdx.x;
    {
        int r = tid >> 2, c4 = (tid & 3) << 4;
        const float* src = W + (size_t)(t * 512 + c0 * 64 + r) * D_DIM + (w << 6) + c4;
#pragma unroll
        for (int j = 0; j < 4; ++j) {
            float4 v = *(const float4*)(src + 4 * j);
            tile[r][c4 + 4 * j + 0] = v.x;
            tile[r][c4 + 4 * j + 1] = v.y;
            tile[r][c4 + 4 * j + 2] = v.z;
            tile[r][c4 + 4 * j + 3] = v.w;
        }
    }
    __syncthreads();
    const int lane = tid & 63, f2 = tid >> 6;
    const int r15 = lane & 15, hi = lane >> 4;
#pragma unroll
    for (int ff = 0; ff < 2; ++ff) {
        int f = f2 * 2 + ff;
        int n = f >> 1, k32 = f & 1;
        int q2 = (c0 * 2 + k32) * 16 + t;
        short8 u;
#pragma unroll
        for (int e = 0; e < 8; ++e)
            u[e] = (short)f2b(tile[k32 * 32 + hi * 8 + e][n * 16 + r15]);
        pk[(size_t)q2 * 2048 + w * 256 + n * 64 + lane] = u;
    }
}

// ---------------------------------------------------------------------------
// Kernel A: windows-GEMM + bias + exact GELU -> hbuf (fp32).
// R9 dataflow + m201-style 8-phase schedule:
//   per phase (2 TSTEPs): {B prefetch + stage chunk + ds_read A-frags}
//     -> s_barrier -> lgkmcnt(0) -> setprio(1) MFMA x32 setprio(0) -> s_barrier
// vmcnt is always counted (B/stage loads stay in flight across barriers).
// Swizzle sw = ((r>>3)&7)^((r>>6)&1): conflict-free fragment reads.
// ---------------------------------------------------------------------------
__global__ __launch_bounds__(512, 1)
void gemm4_kernel(const float* __restrict__ x,
                  const short8* __restrict__ pk,
                  const float* __restrict__ bias,
                  float* __restrict__ hbuf)
{
    __shared__ __align__(16) unsigned char lsA[2][TR3 * ROWB];   // 2 x 74.3 KB

    const int bid = blockIdx.x;
    const int nc  = (bid & 7) >> 2;                 // XCD half -> pk half
    const int g   = ((bid >> 3) << 2) | (bid & 3);  // 0..127
    const int b   = g >> 2;
    const int win0 = (g & 3) << 7;                  // window base (x128)
    const int tid = threadIdx.x;
    const int lane = tid & 63, wid = tid >> 6;
    const int wr = wid >> 2, wc = wid & 3;
    const int r15 = lane & 15, hi = lane >> 4;
    const int boff = ((nc * 4 + wc) << 8) + lane;   // short8 units
    const float* xb = x + (size_t)b * S_LEN * D_DIM;

    f32x4 acc[4][4] = {};
    short8 Ba[8], Bb[8];
    float4 ta[2][2];   // 2 staging chunks in flight, literal-indexed

#define CISSUE(J, Q)                                                           \
    {                                                                          \
        if ((J) < 8 || tid < 32) {                                             \
            const int c_ = tid + ((J) << 9);                                   \
            const int r_ = c_ >> 2, k4_ = c_ & 3;                              \
            int gr_ = (win0 << 3) + r_;                                        \
            if (gr_ > S_LEN - 1) gr_ = S_LEN - 1;                              \
            const float* s_ = xb + (size_t)gr_ * D_DIM + ((Q) << 5) + (k4_ << 3); \
            ta[(J) & 1][0] = *(const float4*)s_;                               \
            ta[(J) & 1][1] = *(const float4*)(s_ + 4);                         \
        }                                                                      \
    }

#define CWRITE(J, DST)                                                         \
    {                                                                          \
        if ((J) < 8 || tid < 32) {                                             \
            const int c_ = tid + ((J) << 9);                                   \
            const int r_ = c_ >> 2, k4_ = c_ & 3;                              \
            const int sw_ = ((r_ >> 3) & 7) ^ ((r_ >> 6) & 1);                 \
            short4v lo_, hh_;                                                  \
            lo_[0] = (short)f2b(ta[(J) & 1][0].x);                             \
            lo_[1] = (short)f2b(ta[(J) & 1][0].y);                             \
            lo_[2] = (short)f2b(ta[(J) & 1][0].z);                             \
            lo_[3] = (short)f2b(ta[(J) & 1][0].w);                             \
            hh_[0] = (short)f2b(ta[(J) & 1][1].x);                             \
            hh_[1] = (short)f2b(ta[(J) & 1][1].y);                             \
            hh_[2] = (short)f2b(ta[(J) & 1][1].z);                             \
            hh_[3] = (short)f2b(ta[(J) & 1][1].w);                             \
            *(short4v*)&(DST)[r_ * ROWB + ((((k4_ << 1)    ) ^ sw_) << 3)] = lo_; \
            *(short4v*)&(DST)[r_ * ROWB + ((((k4_ << 1) | 1) ^ sw_) << 3)] = hh_; \
        }                                                                      \
    }

    // One phase = TSTEPs T0, T0+1. BU holds this phase's B; BL gets next's.
#define PHASE(T0, BU, BL, EXTRA)                                               \
    {                                                                          \
        _Pragma("unroll")                                                      \
        for (int j = 0; j < 8; ++j) {                                          \
            const int q2n = (q16 + (T0) + 2 + (j >> 2)) & 255;                 \
            BL[j] = pk[(size_t)q2n * 2048 + boff + (j & 3) * 64];              \
        }                                                                      \
        EXTRA                                                                  \
        short8 af[8];                                                          \
        _Pragma("unroll")                                                      \
        for (int tt = 0; tt < 2; ++tt) {                                       \
            _Pragma("unroll")                                                  \
            for (int m = 0; m < 4; ++m) {                                      \
                const int wl_ = (wr << 6) + (m << 4) + r15;                    \
                const int r_ = (wl_ << 3) + (T0) + tt;                         \
                const int sw_ = ((r_ >> 3) & 7) ^ ((r_ >> 6) & 1);             \
                const unsigned char* rb_ = La + r_ * ROWB;                     \
                short4v alo = *(const short4v*)&rb_[(((hi << 1)    ) ^ sw_) << 3]; \
                short4v ahi = *(const short4v*)&rb_[(((hi << 1) | 1) ^ sw_) << 3]; \
                af[tt * 4 + m] = __builtin_shufflevector(alo, ahi, 0, 1, 2, 3, 4, 5, 6, 7); \
            }                                                                  \
        }                                                                      \
        __builtin_amdgcn_s_barrier();                                          \
        asm volatile("s_waitcnt lgkmcnt(0)" ::: "memory");                     \
        __builtin_amdgcn_sched_barrier(0);                                     \
        __builtin_amdgcn_s_setprio(1);                                         \
        _Pragma("unroll")                                                      \
        for (int tt = 0; tt < 2; ++tt)                                         \
            _Pragma("unroll")                                                  \
            for (int m = 0; m < 4; ++m)                                        \
                _Pragma("unroll")                                              \
                for (int n = 0; n < 4; ++n)                                    \
                    acc[m][n] = __builtin_amdgcn_mfma_f32_16x16x32_bf16(       \
                        af[tt * 4 + m], BU[tt * 4 + n], acc[m][n], 0, 0, 0);   \
        __builtin_amdgcn_s_setprio(0);                                         \
        __builtin_amdgcn_s_barrier();                                          \
    }

    // ---- prologue: B(phase 0) + stage slice 0 into buf 0 ----
#pragma unroll
    for (int j = 0; j < 8; ++j)
        Ba[j] = pk[(size_t)(j >> 2) * 2048 + boff + (j & 3) * 64];
    CISSUE(0, 0) CISSUE(1, 0) CWRITE(0, lsA[0]) CISSUE(2, 0) CWRITE(1, lsA[0])
    CISSUE(3, 0) CWRITE(2, lsA[0]) CISSUE(4, 0) CWRITE(3, lsA[0])
    CISSUE(5, 0) CWRITE(4, lsA[0]) CISSUE(6, 0) CWRITE(5, lsA[0])
    CISSUE(7, 0) CWRITE(6, lsA[0]) CISSUE(8, 0) CWRITE(7, lsA[0])
    CWRITE(8, lsA[0])
    asm volatile("s_waitcnt lgkmcnt(0)" ::: "memory");
    __builtin_amdgcn_s_barrier();
    __builtin_amdgcn_sched_barrier(0);

    // ---- main loop: 16 K-slices x 8 phases (2 TSTEPs each) ----
    for (int sl = 0; sl < 16; ++sl) {
        const unsigned char* La = lsA[sl & 1];
        unsigned char* Ln = lsA[(sl + 1) & 1];
        const int q16 = sl << 4;
        const int qn = sl + 1;
        const int pf = (sl < 15);

        PHASE(0,  Ba, Bb, { if (pf) { CISSUE(0, qn) CISSUE(1, qn) } })
        PHASE(2,  Bb, Ba, { if (pf) { CWRITE(0, Ln) CISSUE(2, qn) } })
        PHASE(4,  Ba, Bb, { if (pf) { CWRITE(1, Ln) CISSUE(3, qn) } })
        PHASE(6,  Bb, Ba, { if (pf) { CWRITE(2, Ln) CISSUE(4, qn) } })
        PHASE(8,  Ba, Bb, { if (pf) { CWRITE(3, Ln) CISSUE(5, qn) } })
        PHASE(10, Bb, Ba, { if (pf) { CWRITE(4, Ln) CISSUE(6, qn) } })
        PHASE(12, Ba, Bb, { if (pf) { CWRITE(5, Ln) CISSUE(7, qn) CWRITE(6, Ln) } })
        PHASE(14, Bb, Ba, { if (pf) { CISSUE(8, qn) CWRITE(7, Ln) CWRITE(8, Ln) } })
    }
#undef PHASE
#undef CISSUE
#undef CWRITE

    // ---- epilogue: bias + exact GELU -> hbuf[b][win][d] (verified R9) ----
    const int dbase = ((nc * 4 + wc) << 6) + r15;
    float bias4[4];
#pragma unroll
    for (int n = 0; n < 4; ++n)
        bias4[n] = bias[dbase + (n << 4)];
    float* hb = hbuf + (size_t)b * NWIN * D_DIM;
#pragma unroll
    for (int m = 0; m < 4; ++m) {
#pragma unroll
        for (int r = 0; r < 4; ++r) {
            int win = win0 + (wr << 6) + (m << 4) + (hi << 2) + r;
            if (win < NWIN) {
                float* dst = hb + (size_t)win * D_DIM + dbase;
#pragma unroll
                for (int n = 0; n < 4; ++n) {
                    float h = acc[m][n][r] + bias4[n];
                    dst[n << 4] = 0.5f * h * (1.0f + erff(h * 0.70710678118654752f));
                }
            }
        }
    }
}

// ---------------------------------------------------------------------------
// Kernel B: row LayerNorm over D=512. One wave per row, grid-stride. (verified)
// ---------------------------------------------------------------------------
__global__ __launch_bounds__(256, 8)
void ln_kernel(const float* __restrict__ h, const float* __restrict__ gamma,
               const float* __restrict__ beta, float* __restrict__ out, int nrows)
{
    const int lane = threadIdx.x & 63;
    const int wv = blockIdx.x * 4 + (threadIdx.x >> 6);
    const int nw = gridDim.x * 4;
    float gm[8], bt[8];
#pragma unroll
    for (int j = 0; j < 8; ++j) {
        gm[j] = gamma[lane * 8 + j];
        bt[j] = beta[lane * 8 + j];
    }
    for (int row = wv; row < nrows; row += nw) {
        const float* src = h + (size_t)row * D_DIM + lane * 8;
        float4 v0 = *(const float4*)src;
        float4 v1 = *(const float4*)(src + 4);
        float s = v0.x + v0.y + v0.z + v0.w + v1.x + v1.y + v1.z + v1.w;
        float q = v0.x * v0.x + v0.y * v0.y + v0.z * v0.z + v0.w * v0.w +
                  v1.x * v1.x + v1.y * v1.y + v1.z * v1.z + v1.w * v1.w;
#pragma unroll
        for (int msk = 1; msk < 64; msk <<= 1) {
            s += __shfl_xor(s, msk, 64);
            q += __shfl_xor(q, msk, 64);
        }
        float mu  = s * (1.0f / 512.0f);
        float inv = rsqrtf(q * (1.0f / 512.0f) - mu * mu + 1e-5f);
        float o[8] = { v0.x, v0.y, v0.z, v0.w, v1.x, v1.y, v1.z, v1.w };
        float4 r0, r1;
        r0.x = (o[0] - mu) * inv * gm[0] + bt[0];
        r0.y = (o[1] - mu) * inv * gm[1] + bt[1];
        r0.z = (o[2] - mu) * inv * gm[2] + bt[2];
        r0.w = (o[3] - mu) * inv * gm[3] + bt[3];
        r1.x = (o[4] - mu) * inv * gm[4] + bt[4];
        r1.y = (o[5] - mu) * inv * gm[5] + bt[5];
        r1.z = (o[6] - mu) * inv * gm[6] + bt[6];
        r1.w = (o[7] - mu) * inv * gm[7] + bt[7];
        float* dst = out + (size_t)row * D_DIM + lane * 8;
        *(float4*)dst = r0;
        *(float4*)(dst + 4) = r1;
    }
}

// Fallback (tiny ws): naive correct kernel.
__global__ void naive_kernel(const float* __restrict__ x, const float* __restrict__ W,
                             const float* __restrict__ bias, const float* __restrict__ gamma,
                             const float* __restrict__ beta, float* __restrict__ out) {
    __shared__ float hrow[D_DIM];
    __shared__ float red[2];
    const int b = blockIdx.x / NWIN, win = blockIdx.x % NWIN;
    const int d = threadIdx.x;
    float a = 0.f;
    for (int t = 0; t < 16; ++t) {
        const float* xr = x + ((size_t)b * S_LEN + 8 * win + t) * D_DIM;
        const float* wr = W + (size_t)t * D_DIM * D_DIM;
        for (int k = 0; k < D_DIM; ++k) a += xr[k] * wr[(size_t)k * D_DIM + d];
    }
    a += bias[d];
    a = 0.5f * a * (1.0f + erff(a * 0.70710678118654752f));
    hrow[d] = a;
    __syncthreads();
    if (d == 0) {
        float s = 0.f, q = 0.f;
        for (int k = 0; k < D_DIM; ++k) { s += hrow[k]; q += hrow[k] * hrow[k]; }
        float mu = s / D_DIM;
        red[0] = mu; red[1] = rsqrtf(q / D_DIM - mu * mu + 1e-5f);
    }
    __syncthreads();
    out[((size_t)b * NWIN + win) * D_DIM + d] = (a - red[0]) * red[1] * gamma[d] + beta[d];
}

extern "C" void kernel_launch(void* const* d_in, const int* in_sizes, int n_in,
                              void* d_out, int out_size, void* d_ws, size_t ws_size,
                              hipStream_t stream) {
    const float* x     = (const float*)d_in[0];
    const float* W     = (const float*)d_in[1];
    const float* bias  = (const float*)d_in[2];
    const float* gamma = (const float*)d_in[3];
    const float* beta  = (const float*)d_in[4];
    float* out = (float*)d_out;

    const size_t pk_bytes = (size_t)KDIM * D_DIM * sizeof(unsigned short);     // 8 MB
    const size_t h_bytes  = (size_t)32 * NWIN * D_DIM * sizeof(float);         // 33.5 MB

    if (ws_size >= pk_bytes + h_bytes) {          // proven available (R4/R8/R9)
        short8* pk = (short8*)d_ws;
        float* hbuf = (float*)((char*)d_ws + pk_bytes);
        wpack2_kernel<<<1024, 256, 0, stream>>>(W, pk);
        gemm4_kernel<<<256, 512, 0, stream>>>(x, pk, bias, hbuf);
        ln_kernel<<<1024, 256, 0, stream>>>(hbuf, gamma, beta, out, 32 * NWIN);
    } else {
        naive_kernel<<<32 * NWIN, D_DIM, 0, stream>>>(x, W, bias, gamma, beta, out);
    }
}

// Round 11
// 353.552 us; speedup vs baseline: 1.0552x; 1.0552x over previous
//
#include <hip/hip_runtime.h>
#include <hip/hip_bf16.h>
#include <cstdint>

#define S_LEN 4096
#define D_DIM 512
#define NWIN  511
#define KDIM  8192
#define TR5   520                 // 8*64+8 x-rows per A-tile (BM=64)
#define ROWB  72                  // padded row bytes (32 bf16 = 64 B + 8 pad)
#define TR6   520                 // R6 fallback tile rows

typedef __attribute__((ext_vector_type(8))) short short8;
typedef __attribute__((ext_vector_type(4))) short short4v;
typedef __attribute__((ext_vector_type(4))) float f32x4;

#define PH_ELEMS ((size_t)32 * NWIN * D_DIM)   // 8,372,224 floats per K-half

__device__ __forceinline__ unsigned short f2b(float f) {
    union { float f; unsigned int u; } v; v.f = f;
    unsigned int r = v.u + 0x7FFFu + ((v.u >> 16) & 1u);
    return (unsigned short)(r >> 16);
}

// ---------------------------------------------------------------------------
// Pre-pass (verified R8/R9): W [8192][512] fp32 -> bf16 fragments, K=32
// slice-major. q2 = (c0*2+k32)*16 + t. Fragment content:
//   value = W[t*512 + c0*64 + k32*32 + hi*8 + e][64*w + 16*n + r15]
//   at short8 offset q2*2048 + w*256 + n*64 + lane.
// Slice sl=q2>>4 covers x cols [32*sl, +32).
// ---------------------------------------------------------------------------
__global__ void wpack2_kernel(const float* __restrict__ W, short8* __restrict__ pk) {
    __shared__ float tile[64][68];
    const int b2 = blockIdx.x;           // (t*8+c0)*8 + w
    const int s = b2 >> 3, w = b2 & 7;
    const int t = s >> 3, c0 = s & 7;
    const int tid = threadIdx.x;
    {
        int r = tid >> 2, c4 = (tid & 3) << 4;
        const float* src = W + (size_t)(t * 512 + c0 * 64 + r) * D_DIM + (w << 6) + c4;
#pragma unroll
        for (int j = 0; j < 4; ++j) {
            float4 v = *(const float4*)(src + 4 * j);
            tile[r][c4 + 4 * j + 0] = v.x;
            tile[r][c4 + 4 * j + 1] = v.y;
            tile[r][c4 + 4 * j + 2] = v.z;
            tile[r][c4 + 4 * j + 3] = v.w;
        }
    }
    __syncthreads();
    const int lane = tid & 63, f2 = tid >> 6;
    const int r15 = lane & 15, hi = lane >> 4;
#pragma unroll
    for (int ff = 0; ff < 2; ++ff) {
        int f = f2 * 2 + ff;
        int n = f >> 1, k32 = f & 1;
        int q2 = (c0 * 2 + k32) * 16 + t;
        short8 u;
#pragma unroll
        for (int e = 0; e < 8; ++e)
            u[e] = (short)f2b(tile[k32 * 32 + hi * 8 + e][n * 16 + r15]);
        pk[(size_t)q2 * 2048 + w * 256 + n * 64 + lane] = u;
    }
}

// ---------------------------------------------------------------------------
// gemm5: K-SPLIT windows-GEMM -> raw fp32 partials in ph[kh].
// Grid 512 = 32 b x 8 window-groups x 2 K-halves; 512 thr, 8 waves (wave
// tile 64x64, wave wc owns cols [64wc,+64)). 2 blocks/CU (LDS 74.9 KB,
// VGPR capped 128 via launch_bounds(512,4)) -> 4 waves/SIMD cross-block TLP.
// kh = XCD half -> each XCD L2 streams only its 4 MB pk half.
// A: 8 K-slices of 32 cols, 2x37.4 KB LDS dbuf, R10-proven swizzle
//    sw=((r>>3)&7)^((r>>6)&1); issue-early/write-late; ONE barrier/slice.
// ---------------------------------------------------------------------------
__global__ __launch_bounds__(512, 4)
void gemm5_kernel(const float* __restrict__ x,
                  const short8* __restrict__ pk,
                  float* __restrict__ ph)
{
    __shared__ __align__(16) unsigned char lsA[2][TR5 * ROWB];   // 2 x 37.4 KB

    const int bid = blockIdx.x;
    const int kh  = (bid & 7) >> 2;                 // XCD half -> K half
    const int g   = ((bid >> 3) << 2) | (bid & 3);  // 0..255
    const int b   = g >> 3;
    const int n0  = (g & 7) << 6;                   // window base (x64)
    const int tid = threadIdx.x;
    const int lane = tid & 63, wc = tid >> 6;
    const int r15 = lane & 15, hi = lane >> 4;
    const int boff = (wc << 8) + lane;              // short8 units
    const int khb = kh << 7;                        // q2 base
    const float* xb = x + (size_t)b * S_LEN * D_DIM;

    f32x4 acc[4][4] = {};
    short8 Bc[4], Bn[4];
    float4 ta[2][2];   // 2 staging chunks in flight, literal-indexed

#define CISSUE(J, S)                                                           \
    {                                                                          \
        if ((J) < 4 || tid < 32) {                                             \
            const int c_ = tid + ((J) << 9);                                   \
            const int r_ = c_ >> 2, k4_ = c_ & 3;                              \
            int gr_ = (n0 << 3) + r_;                                          \
            if (gr_ > S_LEN - 1) gr_ = S_LEN - 1;                              \
            const float* s_ = xb + (size_t)gr_ * D_DIM + (kh * 256 + (S) * 32) + (k4_ << 3); \
            ta[(J) & 1][0] = *(const float4*)s_;                               \
            ta[(J) & 1][1] = *(const float4*)(s_ + 4);                         \
        }                                                                      \
    }

#define CWRITE(J, DST)                                                         \
    {                                                                          \
        if ((J) < 4 || tid < 32) {                                             \
            const int c_ = tid + ((J) << 9);                                   \
            const int r_ = c_ >> 2, k4_ = c_ & 3;                              \
            const int sw_ = ((r_ >> 3) & 7) ^ ((r_ >> 6) & 1);                 \
            short4v lo_, hh_;                                                  \
            lo_[0] = (short)f2b(ta[(J) & 1][0].x);                             \
            lo_[1] = (short)f2b(ta[(J) & 1][0].y);                             \
            lo_[2] = (short)f2b(ta[(J) & 1][0].z);                             \
            lo_[3] = (short)f2b(ta[(J) & 1][0].w);                             \
            hh_[0] = (short)f2b(ta[(J) & 1][1].x);                             \
            hh_[1] = (short)f2b(ta[(J) & 1][1].y);                             \
            hh_[2] = (short)f2b(ta[(J) & 1][1].z);                             \
            hh_[3] = (short)f2b(ta[(J) & 1][1].w);                             \
            *(short4v*)&(DST)[r_ * ROWB + ((((k4_ << 1)    ) ^ sw_) << 3)] = lo_; \
            *(short4v*)&(DST)[r_ * ROWB + ((((k4_ << 1) | 1) ^ sw_) << 3)] = hh_; \
        }                                                                      \
    }

#define TSTEP(T, LA, BU, BL)                                                   \
    {                                                                          \
        const int q2n = khb + ((s16 + (T) + 1) & 127);                         \
        _Pragma("unroll")                                                      \
        for (int n = 0; n < 4; ++n)                                            \
            BL[n] = pk[(size_t)q2n * 2048 + boff + n * 64];                    \
        __builtin_amdgcn_s_setprio(1);                                         \
        _Pragma("unroll")                                                      \
        for (int m = 0; m < 4; ++m) {                                          \
            const int r_ = (((m << 4) + r15) << 3) + (T);                      \
            const int sw_ = ((r_ >> 3) & 7) ^ ((r_ >> 6) & 1);                 \
            const unsigned char* rb_ = (LA) + r_ * ROWB;                       \
            short4v alo = *(const short4v*)&rb_[(((hi << 1)    ) ^ sw_) << 3]; \
            short4v ahi = *(const short4v*)&rb_[(((hi << 1) | 1) ^ sw_) << 3]; \
            short8 afr = __builtin_shufflevector(alo, ahi, 0, 1, 2, 3, 4, 5, 6, 7); \
            _Pragma("unroll")                                                  \
            for (int n = 0; n < 4; ++n)                                        \
                acc[m][n] = __builtin_amdgcn_mfma_f32_16x16x32_bf16(           \
                    afr, BU[n], acc[m][n], 0, 0, 0);                           \
        }                                                                      \
        __builtin_amdgcn_s_setprio(0);                                         \
    }

    // ---- prologue: B(first q2) in flight, stage slice 0 into buf 0 ----
#pragma unroll
    for (int n = 0; n < 4; ++n)
        Bc[n] = pk[(size_t)khb * 2048 + boff + n * 64];
    CISSUE(0, 0) CISSUE(1, 0) CWRITE(0, lsA[0]) CISSUE(2, 0) CWRITE(1, lsA[0])
    CISSUE(3, 0) CWRITE(2, lsA[0]) CISSUE(4, 0) CWRITE(3, lsA[0]) CWRITE(4, lsA[0])
    asm volatile("s_waitcnt lgkmcnt(0)" ::: "memory");
    __builtin_amdgcn_s_barrier();
    __builtin_amdgcn_sched_barrier(0);

    // ---- main loop: 8 K-slices (32 x-cols each) x 16 t-steps ----
    for (int s = 0; s < 8; ++s) {
        const unsigned char* La = lsA[s & 1];
        unsigned char* Ln = lsA[(s + 1) & 1];
        const int s16 = s << 4;
        const int sn = s + 1;
        const int pf = (s < 7);

        TSTEP(0, La, Bc, Bn)
        if (pf) CISSUE(0, sn)
        TSTEP(1, La, Bn, Bc)
        if (pf) CISSUE(1, sn)
        TSTEP(2, La, Bc, Bn)
        if (pf) { CWRITE(0, Ln) CISSUE(2, sn) }
        TSTEP(3, La, Bn, Bc)
        if (pf) { CWRITE(1, Ln) CISSUE(3, sn) }
        TSTEP(4, La, Bc, Bn)
        if (pf) { CWRITE(2, Ln) CISSUE(4, sn) }
        TSTEP(5, La, Bn, Bc)
        if (pf) CWRITE(3, Ln)
        TSTEP(6, La, Bc, Bn)
        if (pf) CWRITE(4, Ln)
        TSTEP(7, La, Bn, Bc)
        TSTEP(8, La, Bc, Bn)
        TSTEP(9, La, Bn, Bc)
        TSTEP(10, La, Bc, Bn)
        TSTEP(11, La, Bn, Bc)
        TSTEP(12, La, Bc, Bn)
        TSTEP(13, La, Bn, Bc)
        TSTEP(14, La, Bc, Bn)
        TSTEP(15, La, Bn, Bc)

        asm volatile("s_waitcnt lgkmcnt(0)" ::: "memory");
        __builtin_amdgcn_s_barrier();
        __builtin_amdgcn_sched_barrier(0);
    }
#undef TSTEP
#undef CISSUE
#undef CWRITE

    // ---- epilogue: raw fp32 partial sums -> ph[kh][b][win][d] ----
    float* hb = ph + (size_t)kh * PH_ELEMS + (size_t)b * NWIN * D_DIM;
#pragma unroll
    for (int m = 0; m < 4; ++m) {
#pragma unroll
        for (int r = 0; r < 4; ++r) {
            int win = n0 + (m << 4) + (hi << 2) + r;
            if (win < NWIN) {
                float* dst = hb + (size_t)win * D_DIM + (wc << 6) + r15;
#pragma unroll
                for (int n = 0; n < 4; ++n)
                    dst[n << 4] = acc[m][n][r];
            }
        }
    }
}

// ---------------------------------------------------------------------------
// ln2: h = ph0 + ph1 + bias -> exact GELU -> LayerNorm -> out. Wave per row.
// ---------------------------------------------------------------------------
__global__ __launch_bounds__(256, 8)
void ln2_kernel(const float* __restrict__ ph, const float* __restrict__ bias,
                const float* __restrict__ gamma, const float* __restrict__ beta,
                float* __restrict__ out, int nrows)
{
    const int lane = threadIdx.x & 63;
    const int wv = blockIdx.x * 4 + (threadIdx.x >> 6);
    const int nw = gridDim.x * 4;
    float bi[8], gm[8], bt[8];
#pragma unroll
    for (int j = 0; j < 8; ++j) {
        bi[j] = bias[lane * 8 + j];
        gm[j] = gamma[lane * 8 + j];
        bt[j] = beta[lane * 8 + j];
    }
    for (int row = wv; row < nrows; row += nw) {
        const float* s0 = ph + (size_t)row * D_DIM + lane * 8;
        const float* s1 = s0 + PH_ELEMS;
        float4 a0 = *(const float4*)s0;
        float4 a1 = *(const float4*)(s0 + 4);
        float4 b0 = *(const float4*)s1;
        float4 b1 = *(const float4*)(s1 + 4);
        float v[8] = { a0.x + b0.x, a0.y + b0.y, a0.z + b0.z, a0.w + b0.w,
                       a1.x + b1.x, a1.y + b1.y, a1.z + b1.z, a1.w + b1.w };
        float s = 0.f, q = 0.f;
#pragma unroll
        for (int j = 0; j < 8; ++j) {
            float h = v[j] + bi[j];
            float gl = 0.5f * h * (1.0f + erff(h * 0.70710678118654752f));
            v[j] = gl;
            s += gl; q += gl * gl;
        }
#pragma unroll
        for (int msk = 1; msk < 64; msk <<= 1) {
            s += __shfl_xor(s, msk, 64);
            q += __shfl_xor(q, msk, 64);
        }
        float mu  = s * (1.0f / 512.0f);
        float inv = rsqrtf(q * (1.0f / 512.0f) - mu * mu + 1e-5f);
        float4 r0, r1;
        r0.x = (v[0] - mu) * inv * gm[0] + bt[0];
        r0.y = (v[1] - mu) * inv * gm[1] + bt[1];
        r0.z = (v[2] - mu) * inv * gm[2] + bt[2];
        r0.w = (v[3] - mu) * inv * gm[3] + bt[3];
        r1.x = (v[4] - mu) * inv * gm[4] + bt[4];
        r1.y = (v[5] - mu) * inv * gm[5] + bt[5];
        r1.z = (v[6] - mu) * inv * gm[6] + bt[6];
        r1.w = (v[7] - mu) * inv * gm[7] + bt[7];
        float* dst = out + (size_t)row * D_DIM + lane * 8;
        *(float4*)dst = r0;
        *(float4*)(dst + 4) = r1;
    }
}

// ===========================================================================
// FALLBACK TIER 1 (ws >= 8 MB only): R6's verified fused kernel, verbatim.
// ===========================================================================
__global__ void wpack_c0_kernel(const float* __restrict__ W, short8* __restrict__ pk) {
    __shared__ float tile[64][68];
    const int b2 = blockIdx.x;           // s*8 + w
    const int s = b2 >> 3, w = b2 & 7;
    const int t = s >> 3, c0 = s & 7;
    const int q = c0 * 16 + t;           // c0-major slot
    const int tid = threadIdx.x;
    {
        int r = tid >> 2, c4 = (tid & 3) << 4;
        const float* src = W + (size_t)(t * 512 + c0 * 64 + r) * D_DIM + (w << 6) + c4;
#pragma unroll
        for (int j = 0; j < 4; ++j) {
            float4 v = *(const float4*)(src + 4 * j);
            tile[r][c4 + 4 * j + 0] = v.x;
            tile[r][c4 + 4 * j + 1] = v.y;
            tile[r][c4 + 4 * j + 2] = v.z;
            tile[r][c4 + 4 * j + 3] = v.w;
        }
    }
    __syncthreads();
    const int lane = tid & 63, f2 = tid >> 6;
#pragma unroll
    for (int ff = 0; ff < 2; ++ff) {
        int f = f2 * 2 + ff;
        int n = f >> 1, k32 = f & 1;
        short8 u;
#pragma unroll
        for (int e = 0; e < 8; ++e)
            u[e] = (short)f2b(tile[k32 * 32 + (lane >> 4) * 8 + e][n * 16 + (lane & 15)]);
        pk[((size_t)q * 8 + w) * 8 * 64 + (size_t)f * 64 + lane] = u;
    }
}

__device__ __forceinline__ void load_b8(const short8* __restrict__ pk, int q, int wslot,
                                        int lane, short8 (&bf)[4][2]) {
    const short8* base = pk + ((size_t)(q * 8 + wslot) * 8) * 64 + lane;
#pragma unroll
    for (int n = 0; n < 4; ++n)
#pragma unroll
        for (int k32 = 0; k32 < 2; ++k32)
            bf[n][k32] = base[(n * 2 + k32) * 64];
}

__global__ __launch_bounds__(512, 2)
void fusedR6_kernel(const float* __restrict__ x,
                    const short8* __restrict__ pk,
                    const float* __restrict__ bias,
                    const float* __restrict__ gamma,
                    const float* __restrict__ beta,
                    float* __restrict__ out)
{
    __shared__ __align__(16) unsigned short lsA6[2][TR6 * 64];
    __shared__ float redS[8][64];
    __shared__ float redQ[8][64];

    const int blk = blockIdx.x;
    const int b  = blk >> 3;
    const int n0 = (blk & 7) << 6;
    const int tid = threadIdx.x;
    const int lane = tid & 63;
    const int wid  = tid >> 6;
    const int r15 = lane & 15, hi = lane >> 4;
    const float* xb = x + (size_t)b * S_LEN * D_DIM;

    f32x4 acc[4][4] = {};
    short8 bc[4][2], bn[4][2];
    float4 ta[9][2];

#define FCISSUE(J, C0N)                                                        \
    {                                                                          \
        if ((J) < 8 || tid < 64) {                                             \
            const int slot = tid + ((J) << 9);                                 \
            const int r = slot >> 3, k8 = slot & 7;                            \
            int grow = 8 * n0 + r;                                             \
            if (grow > S_LEN - 1) grow = S_LEN - 1;                            \
            const float* src = xb + (size_t)grow * D_DIM + ((C0N) << 6) + (k8 << 3); \
            ta[J][0] = *(const float4*)src;                                    \
            ta[J][1] = *(const float4*)(src + 4);                              \
        }                                                                      \
    }

#define FCWRITE(J, DST)                                                        \
    {                                                                          \
        if ((J) < 8 || tid < 64) {                                             \
            const int slot = tid + ((J) << 9);                                 \
            const int r = slot >> 3, k8 = slot & 7;                            \
            short8 u;                                                          \
            u[0] = (short)f2b(ta[J][0].x); u[1] = (short)f2b(ta[J][0].y);      \
            u[2] = (short)f2b(ta[J][0].z); u[3] = (short)f2b(ta[J][0].w);      \
            u[4] = (short)f2b(ta[J][1].x); u[5] = (short)f2b(ta[J][1].y);      \
            u[6] = (short)f2b(ta[J][1].z); u[7] = (short)f2b(ta[J][1].w);      \
            *(short8*)&(DST)[(r << 6) + ((k8 ^ ((r >> 3) & 7)) << 3)] = u;     \
        }                                                                      \
    }

#define FTSTEP(T, LA, BCUR, BNXT)                                              \
    {                                                                          \
        const int qn = (c0 * 16 + (T) + 1) & 127;                              \
        load_b8(pk, qn, wid, lane, BNXT);                                      \
        short8 afr[4][2];                                                      \
        _Pragma("unroll")                                                      \
        for (int m = 0; m < 4; ++m) {                                          \
            const int row = (((m << 4) + r15) << 3) + (T);                     \
            const int sb  = (r15 + ((T) >> 3)) & 7;                            \
            _Pragma("unroll")                                                  \
            for (int k32 = 0; k32 < 2; ++k32)                                  \
                afr[m][k32] = *(const short8*)&(LA)[(row << 6) +               \
                                   ((((k32 << 2) + hi) ^ sb) << 3)];           \
        }                                                                      \
        _Pragma("unroll")                                                      \
        for (int k32 = 0; k32 < 2; ++k32)                                      \
            _Pragma("unroll")                                                  \
            for (int m = 0; m < 4; ++m)                                        \
                _Pragma("unroll")                                              \
                for (int n = 0; n < 4; ++n)                                    \
                    acc[m][n] = __builtin_amdgcn_mfma_f32_16x16x32_bf16(       \
                        afr[m][k32], BCUR[n][k32], acc[m][n], 0, 0, 0);        \
    }

    load_b8(pk, 0, wid, lane, bc);
    FCISSUE(0, 0) FCISSUE(1, 0) FCISSUE(2, 0) FCISSUE(3, 0) FCISSUE(4, 0)
    FCISSUE(5, 0) FCISSUE(6, 0) FCISSUE(7, 0) FCISSUE(8, 0)
    FCWRITE(0, lsA6[0]) FCWRITE(1, lsA6[0]) FCWRITE(2, lsA6[0]) FCWRITE(3, lsA6[0])
    FCWRITE(4, lsA6[0]) FCWRITE(5, lsA6[0]) FCWRITE(6, lsA6[0]) FCWRITE(7, lsA6[0])
    FCWRITE(8, lsA6[0])
    asm volatile("s_waitcnt lgkmcnt(0)" ::: "memory");
    __builtin_amdgcn_s_barrier();
    __builtin_amdgcn_sched_barrier(0);

    for (int c0 = 0; c0 < 8; ++c0) {
        const unsigned short* La = lsA6[c0 & 1];
        unsigned short* Ln = lsA6[(c0 + 1) & 1];
        const int c0n = c0 + 1;
        const int pf = (c0 < 7);

        FTSTEP(0, La, bc, bn)
        if (pf) { FCISSUE(0, c0n) FCISSUE(1, c0n) }
        FTSTEP(1, La, bn, bc)
        FTSTEP(2, La, bc, bn)
        if (pf) { FCISSUE(2, c0n) FCISSUE(3, c0n) }
        FTSTEP(3, La, bn, bc)
        FTSTEP(4, La, bc, bn)
        if (pf) { FCISSUE(4, c0n) FCISSUE(5, c0n) }
        FTSTEP(5, La, bn, bc)
        FTSTEP(6, La, bc, bn)
        if (pf) { FCISSUE(6, c0n) FCISSUE(7, c0n) }
        FTSTEP(7, La, bn, bc)
        FTSTEP(8, La, bc, bn)
        if (pf) { FCISSUE(8, c0n) FCWRITE(0, Ln) FCWRITE(1, Ln) }
        FTSTEP(9, La, bn, bc)
        FTSTEP(10, La, bc, bn)
        if (pf) { FCWRITE(2, Ln) FCWRITE(3, Ln) }
        FTSTEP(11, La, bn, bc)
        FTSTEP(12, La, bc, bn)
        if (pf) { FCWRITE(4, Ln) FCWRITE(5, Ln) }
        FTSTEP(13, La, bn, bc)
        FTSTEP(14, La, bc, bn)
        if (pf) { FCWRITE(6, Ln) FCWRITE(7, Ln) FCWRITE(8, Ln) }
        FTSTEP(15, La, bn, bc)

        asm volatile("s_waitcnt lgkmcnt(0)" ::: "memory");
        __builtin_amdgcn_s_barrier();
        __builtin_amdgcn_sched_barrier(0);
    }
#undef FTSTEP
#undef FCISSUE
#undef FCWRITE

    float bias4[4], gam4[4], bet4[4];
#pragma unroll
    for (int n = 0; n < 4; ++n) {
        int d = (wid << 6) + 16 * n + r15;
        bias4[n] = bias[d]; gam4[n] = gamma[d]; bet4[n] = beta[d];
    }
    float sum_[4][4], sq_[4][4];
#pragma unroll
    for (int m = 0; m < 4; ++m)
#pragma unroll
        for (int r = 0; r < 4; ++r) { sum_[m][r] = 0.f; sq_[m][r] = 0.f; }
#pragma unroll
    for (int m = 0; m < 4; ++m)
#pragma unroll
        for (int n = 0; n < 4; ++n)
#pragma unroll
            for (int r = 0; r < 4; ++r) {
                float h = acc[m][n][r] + bias4[n];
                float g = 0.5f * h * (1.0f + erff(h * 0.70710678118654752f));
                acc[m][n][r] = g;
                sum_[m][r] += g;
                sq_[m][r]  += g * g;
            }
#pragma unroll
    for (int m = 0; m < 4; ++m)
#pragma unroll
        for (int r = 0; r < 4; ++r) {
            float sv = sum_[m][r], qv = sq_[m][r];
#pragma unroll
            for (int msk = 1; msk < 16; msk <<= 1) {
                sv += __shfl_xor(sv, msk, 64);
                qv += __shfl_xor(qv, msk, 64);
            }
            sum_[m][r] = sv; sq_[m][r] = qv;
        }
    if (r15 == 0) {
#pragma unroll
        for (int m = 0; m < 4; ++m)
#pragma unroll
            for (int r = 0; r < 4; ++r) {
                int row16 = 16 * m + hi * 4 + r;
                redS[wid][row16] = sum_[m][r];
                redQ[wid][row16] = sq_[m][r];
            }
    }
    __syncthreads();
#pragma unroll
    for (int m = 0; m < 4; ++m) {
#pragma unroll
        for (int r = 0; r < 4; ++r) {
            int row16 = 16 * m + hi * 4 + r;
            float sv = 0.f, qv = 0.f;
#pragma unroll
            for (int w = 0; w < 8; ++w) { sv += redS[w][row16]; qv += redQ[w][row16]; }
            float mu  = sv * (1.0f / 512.0f);
            float var = qv * (1.0f / 512.0f) - mu * mu;
            float inv = rsqrtf(var + 1e-5f);
            int win = n0 + row16;
            if (win < NWIN) {
                size_t obase = ((size_t)b * NWIN + win) * D_DIM;
#pragma unroll
                for (int n = 0; n < 4; ++n) {
                    int d = (wid << 6) + 16 * n + r15;
                    out[obase + d] = (acc[m][n][r] - mu) * inv * gam4[n] + bet4[n];
                }
            }
        }
    }
}

// Fallback tier 2 (tiny ws): naive correct kernel.
__global__ void naive_kernel(const float* __restrict__ x, const float* __restrict__ W,
                             const float* __restrict__ bias, const float* __restrict__ gamma,
                             const float* __restrict__ beta, float* __restrict__ out) {
    __shared__ float hrow[D_DIM];
    __shared__ float red[2];
    const int b = blockIdx.x / NWIN, win = blockIdx.x % NWIN;
    const int d = threadIdx.x;
    float a = 0.f;
    for (int t = 0; t < 16; ++t) {
        const float* xr = x + ((size_t)b * S_LEN + 8 * win + t) * D_DIM;
        const float* wr = W + (size_t)t * D_DIM * D_DIM;
        for (int k = 0; k < D_DIM; ++k) a += xr[k] * wr[(size_t)k * D_DIM + d];
    }
    a += bias[d];
    a = 0.5f * a * (1.0f + erff(a * 0.70710678118654752f));
    hrow[d] = a;
    __syncthreads();
    if (d == 0) {
        float s = 0.f, q = 0.f;
        for (int k = 0; k < D_DIM; ++k) { s += hrow[k]; q += hrow[k] * hrow[k]; }
        float mu = s / D_DIM;
        red[0] = mu; red[1] = rsqrtf(q / D_DIM - mu * mu + 1e-5f);
    }
    __syncthreads();
    out[((size_t)b * NWIN + win) * D_DIM + d] = (a - red[0]) * red[1] * gamma[d] + beta[d];
}

extern "C" void kernel_launch(void* const* d_in, const int* in_sizes, int n_in,
                              void* d_out, int out_size, void* d_ws, size_t ws_size,
                              hipStream_t stream) {
    const float* x     = (const float*)d_in[0];
    const float* W     = (const float*)d_in[1];
    const float* bias  = (const float*)d_in[2];
    const float* gamma = (const float*)d_in[3];
    const float* beta  = (const float*)d_in[4];
    float* out = (float*)d_out;

    const size_t pk_bytes = (size_t)KDIM * D_DIM * sizeof(unsigned short);   // 8 MB
    const size_t ph_bytes = 2 * PH_ELEMS * sizeof(float);                    // 67 MB

    if (ws_size >= pk_bytes + ph_bytes) {
        short8* pk = (short8*)d_ws;
        float* ph = (float*)((char*)d_ws + pk_bytes);
        wpack2_kernel<<<1024, 256, 0, stream>>>(W, pk);
        gemm5_kernel<<<512, 512, 0, stream>>>(x, pk, ph);
        ln2_kernel<<<1024, 256, 0, stream>>>(ph, bias, gamma, beta, out, 32 * NWIN);
    } else if (ws_size >= pk_bytes) {
        short8* pk = (short8*)d_ws;
        wpack_c0_kernel<<<1024, 256, 0, stream>>>(W, pk);
        fusedR6_kernel<<<256, 512, 0, stream>>>(x, pk, bias, gamma, beta, out);
    } else {
        naive_kernel<<<32 * NWIN, D_DIM, 0, stream>>>(x, W, bias, gamma, beta, out);
    }
}

// Round 12
// 189.669 us; speedup vs baseline: 1.9670x; 1.8640x over previous
//
#include <hip/hip_runtime.h>
#include <hip/hip_bf16.h>
#include <cstdint>

#define S_LEN 4096
#define D_DIM 512
#define NWIN  511
#define KDIM  8192
#define TR5   520                 // 8*64+8 x-rows per A-tile (BM=64)
#define ROWB  64                  // row bytes: 32 bf16, XOR-swizzled 8B slots
#define TR6   520                 // R6 fallback tile rows

typedef __attribute__((ext_vector_type(8))) short short8;
typedef __attribute__((ext_vector_type(4))) short short4v;
typedef __attribute__((ext_vector_type(4))) float f32x4;

#define PH_ELEMS ((size_t)32 * NWIN * D_DIM)   // floats per K-half partial

__device__ __forceinline__ unsigned short f2b(float f) {
    union { float f; unsigned int u; } v; v.f = f;
    unsigned int r = v.u + 0x7FFFu + ((v.u >> 16) & 1u);
    return (unsigned short)(r >> 16);
}

// ---------------------------------------------------------------------------
// Pre-pass (verified R8-R11): W [8192][512] fp32 -> bf16 fragments, K=32
// slice-major. q2 = (c0*2+k32)*16 + t. Fragment content:
//   value = W[t*512 + c0*64 + k32*32 + hi*8 + e][64*w + 16*n + r15]
//   at short8 offset q2*2048 + w*256 + n*64 + lane.
// ---------------------------------------------------------------------------
__global__ void wpack2_kernel(const float* __restrict__ W, short8* __restrict__ pk) {
    __shared__ float tile[64][68];
    const int b2 = blockIdx.x;           // (t*8+c0)*8 + w
    const int s = b2 >> 3, w = b2 & 7;
    const int t = s >> 3, c0 = s & 7;
    const int tid = threadIdx.x;
    {
        int r = tid >> 2, c4 = (tid & 3) << 4;
        const float* src = W + (size_t)(t * 512 + c0 * 64 + r) * D_DIM + (w << 6) + c4;
#pragma unroll
        for (int j = 0; j < 4; ++j) {
            float4 v = *(const float4*)(src + 4 * j);
            tile[r][c4 + 4 * j + 0] = v.x;
            tile[r][c4 + 4 * j + 1] = v.y;
            tile[r][c4 + 4 * j + 2] = v.z;
            tile[r][c4 + 4 * j + 3] = v.w;
        }
    }
    __syncthreads();
    const int lane = tid & 63, f2 = tid >> 6;
    const int r15 = lane & 15, hi = lane >> 4;
#pragma unroll
    for (int ff = 0; ff < 2; ++ff) {
        int f = f2 * 2 + ff;
        int n = f >> 1, k32 = f & 1;
        int q2 = (c0 * 2 + k32) * 16 + t;
        short8 u;
#pragma unroll
        for (int e = 0; e < 8; ++e)
            u[e] = (short)f2b(tile[k32 * 32 + hi * 8 + e][n * 16 + r15]);
        pk[(size_t)q2 * 2048 + w * 256 + n * 64 + lane] = u;
    }
}

// ---------------------------------------------------------------------------
// gemm6: K-SPLIT windows-GEMM -> raw fp32 partials in ph[kh].  (R9 dataflow)
// Grid 512 = 32 b x 8 window-groups x 2 K-halves; 512 thr, 8 waves (wave
// tile 64x64). kh = XCD half -> each XCD L2 streams only its 4 MB pk half.
// Fixes vs R9: (1) ROWB=64 + R10-proven swizzle ((r>>3)&7)^((r>>6)&1) on
// write AND read (conflicts 18.9M -> ~2M); (2) DEPTH-2 B prefetch over 4
// rotating register buffers (covers ~600cy L2 latency); (3) launch_bounds
// (512,1) so no VGPR cap (R11's (512,4) caused the 433MB spill).
// ---------------------------------------------------------------------------
__global__ __launch_bounds__(512, 1)
void gemm6_kernel(const float* __restrict__ x,
                  const short8* __restrict__ pk,
                  float* __restrict__ ph)
{
    __shared__ __align__(16) unsigned char lsA[2][TR5 * ROWB];   // 2 x 33.3 KB

    const int bid = blockIdx.x;
    const int kh  = (bid & 7) >> 2;                 // XCD half -> K half
    const int g   = ((bid >> 3) << 2) | (bid & 3);  // 0..255
    const int b   = g >> 3;
    const int n0  = (g & 7) << 6;                   // window base (x64)
    const int tid = threadIdx.x;
    const int lane = tid & 63, wc = tid >> 6;
    const int r15 = lane & 15, hi = lane >> 4;
    const int boff = (wc << 8) + lane;              // short8 units
    const int khb = kh << 7;                        // q2 base
    const float* xb = x + (size_t)b * S_LEN * D_DIM;

    f32x4 acc[4][4] = {};
    short8 B0[4], B1[4], B2[4], B3[4];
    float4 ta[2][2];   // 2 staging chunks in flight, literal-indexed

#define CISSUE(J, S)                                                           \
    {                                                                          \
        if ((J) < 4 || tid < 32) {                                             \
            const int c_ = tid + ((J) << 9);                                   \
            const int r_ = c_ >> 2, k4_ = c_ & 3;                              \
            int gr_ = (n0 << 3) + r_;                                          \
            if (gr_ > S_LEN - 1) gr_ = S_LEN - 1;                              \
            const float* s_ = xb + (size_t)gr_ * D_DIM + (kh * 256 + (S) * 32) + (k4_ << 3); \
            ta[(J) & 1][0] = *(const float4*)s_;                               \
            ta[(J) & 1][1] = *(const float4*)(s_ + 4);                         \
        }                                                                      \
    }

#define CWRITE(J, DST)                                                         \
    {                                                                          \
        if ((J) < 4 || tid < 32) {                                             \
            const int c_ = tid + ((J) << 9);                                   \
            const int r_ = c_ >> 2, k4_ = c_ & 3;                              \
            const int sw_ = ((r_ >> 3) & 7) ^ ((r_ >> 6) & 1);                 \
            short4v lo_, hh_;                                                  \
            lo_[0] = (short)f2b(ta[(J) & 1][0].x);                             \
            lo_[1] = (short)f2b(ta[(J) & 1][0].y);                             \
            lo_[2] = (short)f2b(ta[(J) & 1][0].z);                             \
            lo_[3] = (short)f2b(ta[(J) & 1][0].w);                             \
            hh_[0] = (short)f2b(ta[(J) & 1][1].x);                             \
            hh_[1] = (short)f2b(ta[(J) & 1][1].y);                             \
            hh_[2] = (short)f2b(ta[(J) & 1][1].z);                             \
            hh_[3] = (short)f2b(ta[(J) & 1][1].w);                             \
            *(short4v*)&(DST)[(r_ << 6) + ((((k4_ << 1)    ) ^ sw_) << 3)] = lo_; \
            *(short4v*)&(DST)[(r_ << 6) + ((((k4_ << 1) | 1) ^ sw_) << 3)] = hh_; \
        }                                                                      \
    }

#define TSTEP(T, LA, BU, BL)                                                   \
    {                                                                          \
        const int q2n = khb + ((s16 + (T) + 2) & 127);                         \
        _Pragma("unroll")                                                      \
        for (int n = 0; n < 4; ++n)                                            \
            BL[n] = pk[(size_t)q2n * 2048 + boff + n * 64];                    \
        __builtin_amdgcn_s_setprio(1);                                         \
        _Pragma("unroll")                                                      \
        for (int m = 0; m < 4; ++m) {                                          \
            const int r_ = (((m << 4) + r15) << 3) + (T);                      \
            const int sw_ = ((r_ >> 3) & 7) ^ ((r_ >> 6) & 1);                 \
            const unsigned char* rb_ = (LA) + (r_ << 6);                       \
            short4v alo = *(const short4v*)&rb_[(((hi << 1)    ) ^ sw_) << 3]; \
            short4v ahi = *(const short4v*)&rb_[(((hi << 1) | 1) ^ sw_) << 3]; \
            short8 afr = __builtin_shufflevector(alo, ahi, 0, 1, 2, 3, 4, 5, 6, 7); \
            _Pragma("unroll")                                                  \
            for (int n = 0; n < 4; ++n)                                        \
                acc[m][n] = __builtin_amdgcn_mfma_f32_16x16x32_bf16(           \
                    afr, BU[n], acc[m][n], 0, 0, 0);                           \
        }                                                                      \
        __builtin_amdgcn_s_setprio(0);                                         \
    }

    // ---- prologue: B(q0),B(q1) in flight, stage slice 0 into buf 0 ----
#pragma unroll
    for (int n = 0; n < 4; ++n) {
        B0[n] = pk[(size_t)khb * 2048 + boff + n * 64];
        B1[n] = pk[(size_t)(khb + 1) * 2048 + boff + n * 64];
    }
    CISSUE(0, 0) CISSUE(1, 0) CWRITE(0, lsA[0]) CISSUE(2, 0) CWRITE(1, lsA[0])
    CISSUE(3, 0) CWRITE(2, lsA[0]) CISSUE(4, 0) CWRITE(3, lsA[0]) CWRITE(4, lsA[0])
    asm volatile("s_waitcnt lgkmcnt(0)" ::: "memory");
    __builtin_amdgcn_s_barrier();
    __builtin_amdgcn_sched_barrier(0);

    // ---- main loop: 8 K-slices (32 x-cols each) x 16 t-steps ----
    for (int s = 0; s < 8; ++s) {
        const unsigned char* La = lsA[s & 1];
        unsigned char* Ln = lsA[(s + 1) & 1];
        const int s16 = s << 4;
        const int sn = s + 1;
        const int pf = (s < 7);

        TSTEP(0, La, B0, B2)
        if (pf) CISSUE(0, sn)
        TSTEP(1, La, B1, B3)
        if (pf) CISSUE(1, sn)
        TSTEP(2, La, B2, B0)
        if (pf) { CWRITE(0, Ln) CISSUE(2, sn) }
        TSTEP(3, La, B3, B1)
        if (pf) { CWRITE(1, Ln) CISSUE(3, sn) }
        TSTEP(4, La, B0, B2)
        if (pf) { CWRITE(2, Ln) CISSUE(4, sn) }
        TSTEP(5, La, B1, B3)
        if (pf) CWRITE(3, Ln)
        TSTEP(6, La, B2, B0)
        if (pf) CWRITE(4, Ln)
        TSTEP(7, La, B3, B1)
        TSTEP(8, La, B0, B2)
        TSTEP(9, La, B1, B3)
        TSTEP(10, La, B2, B0)
        TSTEP(11, La, B3, B1)
        TSTEP(12, La, B0, B2)
        TSTEP(13, La, B1, B3)
        TSTEP(14, La, B2, B0)
        TSTEP(15, La, B3, B1)

        asm volatile("s_waitcnt lgkmcnt(0)" ::: "memory");
        __builtin_amdgcn_s_barrier();
        __builtin_amdgcn_sched_barrier(0);
    }
#undef TSTEP
#undef CISSUE
#undef CWRITE

    // ---- epilogue: raw fp32 partial sums -> ph[kh][b][win][d] ----
    float* hb = ph + (size_t)kh * PH_ELEMS + (size_t)b * NWIN * D_DIM;
#pragma unroll
    for (int m = 0; m < 4; ++m) {
#pragma unroll
        for (int r = 0; r < 4; ++r) {
            int win = n0 + (m << 4) + (hi << 2) + r;
            if (win < NWIN) {
                float* dst = hb + (size_t)win * D_DIM + (wc << 6) + r15;
#pragma unroll
                for (int n = 0; n < 4; ++n)
                    dst[n << 4] = acc[m][n][r];
            }
        }
    }
}

// ---------------------------------------------------------------------------
// ln2: h = ph0 + ph1 + bias -> exact GELU -> LayerNorm -> out. Wave per row.
// ---------------------------------------------------------------------------
__global__ __launch_bounds__(256, 8)
void ln2_kernel(const float* __restrict__ ph, const float* __restrict__ bias,
                const float* __restrict__ gamma, const float* __restrict__ beta,
                float* __restrict__ out, int nrows)
{
    const int lane = threadIdx.x & 63;
    const int wv = blockIdx.x * 4 + (threadIdx.x >> 6);
    const int nw = gridDim.x * 4;
    float bi[8], gm[8], bt[8];
#pragma unroll
    for (int j = 0; j < 8; ++j) {
        bi[j] = bias[lane * 8 + j];
        gm[j] = gamma[lane * 8 + j];
        bt[j] = beta[lane * 8 + j];
    }
    for (int row = wv; row < nrows; row += nw) {
        const float* s0 = ph + (size_t)row * D_DIM + lane * 8;
        const float* s1 = s0 + PH_ELEMS;
        float4 a0 = *(const float4*)s0;
        float4 a1 = *(const float4*)(s0 + 4);
        float4 b0 = *(const float4*)s1;
        float4 b1 = *(const float4*)(s1 + 4);
        float v[8] = { a0.x + b0.x, a0.y + b0.y, a0.z + b0.z, a0.w + b0.w,
                       a1.x + b1.x, a1.y + b1.y, a1.z + b1.z, a1.w + b1.w };
        float s = 0.f, q = 0.f;
#pragma unroll
        for (int j = 0; j < 8; ++j) {
            float h = v[j] + bi[j];
            float gl = 0.5f * h * (1.0f + erff(h * 0.70710678118654752f));
            v[j] = gl;
            s += gl; q += gl * gl;
        }
#pragma unroll
        for (int msk = 1; msk < 64; msk <<= 1) {
            s += __shfl_xor(s, msk, 64);
            q += __shfl_xor(q, msk, 64);
        }
        float mu  = s * (1.0f / 512.0f);
        float inv = rsqrtf(q * (1.0f / 512.0f) - mu * mu + 1e-5f);
        float4 r0, r1;
        r0.x = (v[0] - mu) * inv * gm[0] + bt[0];
        r0.y = (v[1] - mu) * inv * gm[1] + bt[1];
        r0.z = (v[2] - mu) * inv * gm[2] + bt[2];
        r0.w = (v[3] - mu) * inv * gm[3] + bt[3];
        r1.x = (v[4] - mu) * inv * gm[4] + bt[4];
        r1.y = (v[5] - mu) * inv * gm[5] + bt[5];
        r1.z = (v[6] - mu) * inv * gm[6] + bt[6];
        r1.w = (v[7] - mu) * inv * gm[7] + bt[7];
        float* dst = out + (size_t)row * D_DIM + lane * 8;
        *(float4*)dst = r0;
        *(float4*)(dst + 4) = r1;
    }
}

// ===========================================================================
// FALLBACK TIER 1 (ws >= 8 MB only): R6's verified fused kernel, verbatim.
// ===========================================================================
__global__ void wpack_c0_kernel(const float* __restrict__ W, short8* __restrict__ pk) {
    __shared__ float tile[64][68];
    const int b2 = blockIdx.x;           // s*8 + w
    const int s = b2 >> 3, w = b2 & 7;
    const int t = s >> 3, c0 = s & 7;
    const int q = c0 * 16 + t;           // c0-major slot
    const int tid = threadIdx.x;
    {
        int r = tid >> 2, c4 = (tid & 3) << 4;
        const float* src = W + (size_t)(t * 512 + c0 * 64 + r) * D_DIM + (w << 6) + c4;
#pragma unroll
        for (int j = 0; j < 4; ++j) {
            float4 v = *(const float4*)(src + 4 * j);
            tile[r][c4 + 4 * j + 0] = v.x;
            tile[r][c4 + 4 * j + 1] = v.y;
            tile[r][c4 + 4 * j + 2] = v.z;
            tile[r][c4 + 4 * j + 3] = v.w;
        }
    }
    __syncthreads();
    const int lane = tid & 63, f2 = tid >> 6;
#pragma unroll
    for (int ff = 0; ff < 2; ++ff) {
        int f = f2 * 2 + ff;
        int n = f >> 1, k32 = f & 1;
        short8 u;
#pragma unroll
        for (int e = 0; e < 8; ++e)
            u[e] = (short)f2b(tile[k32 * 32 + (lane >> 4) * 8 + e][n * 16 + (lane & 15)]);
        pk[((size_t)q * 8 + w) * 8 * 64 + (size_t)f * 64 + lane] = u;
    }
}

__device__ __forceinline__ void load_b8(const short8* __restrict__ pk, int q, int wslot,
                                        int lane, short8 (&bf)[4][2]) {
    const short8* base = pk + ((size_t)(q * 8 + wslot) * 8) * 64 + lane;
#pragma unroll
    for (int n = 0; n < 4; ++n)
#pragma unroll
        for (int k32 = 0; k32 < 2; ++k32)
            bf[n][k32] = base[(n * 2 + k32) * 64];
}

__global__ __launch_bounds__(512, 2)
void fusedR6_kernel(const float* __restrict__ x,
                    const short8* __restrict__ pk,
                    const float* __restrict__ bias,
                    const float* __restrict__ gamma,
                    const float* __restrict__ beta,
                    float* __restrict__ out)
{
    __shared__ __align__(16) unsigned short lsA6[2][TR6 * 64];
    __shared__ float redS[8][64];
    __shared__ float redQ[8][64];

    const int blk = blockIdx.x;
    const int b  = blk >> 3;
    const int n0 = (blk & 7) << 6;
    const int tid = threadIdx.x;
    const int lane = tid & 63;
    const int wid  = tid >> 6;
    const int r15 = lane & 15, hi = lane >> 4;
    const float* xb = x + (size_t)b * S_LEN * D_DIM;

    f32x4 acc[4][4] = {};
    short8 bc[4][2], bn[4][2];
    float4 ta[9][2];

#define FCISSUE(J, C0N)                                                        \
    {                                                                          \
        if ((J) < 8 || tid < 64) {                                             \
            const int slot = tid + ((J) << 9);                                 \
            const int r = slot >> 3, k8 = slot & 7;                            \
            int grow = 8 * n0 + r;                                             \
            if (grow > S_LEN - 1) grow = S_LEN - 1;                            \
            const float* src = xb + (size_t)grow * D_DIM + ((C0N) << 6) + (k8 << 3); \
            ta[J][0] = *(const float4*)src;                                    \
            ta[J][1] = *(const float4*)(src + 4);                              \
        }                                                                      \
    }

#define FCWRITE(J, DST)                                                        \
    {                                                                          \
        if ((J) < 8 || tid < 64) {                                             \
            const int slot = tid + ((J) << 9);                                 \
            const int r = slot >> 3, k8 = slot & 7;                            \
            short8 u;                                                          \
            u[0] = (short)f2b(ta[J][0].x); u[1] = (short)f2b(ta[J][0].y);      \
            u[2] = (short)f2b(ta[J][0].z); u[3] = (short)f2b(ta[J][0].w);      \
            u[4] = (short)f2b(ta[J][1].x); u[5] = (short)f2b(ta[J][1].y);      \
            u[6] = (short)f2b(ta[J][1].z); u[7] = (short)f2b(ta[J][1].w);      \
            *(short8*)&(DST)[(r << 6) + ((k8 ^ ((r >> 3) & 7)) << 3)] = u;     \
        }                                                                      \
    }

#define FTSTEP(T, LA, BCUR, BNXT)                                              \
    {                                                                          \
        const int qn = (c0 * 16 + (T) + 1) & 127;                              \
        load_b8(pk, qn, wid, lane, BNXT);                                      \
        short8 afr[4][2];                                                      \
        _Pragma("unroll")                                                      \
        for (int m = 0; m < 4; ++m) {                                          \
            const int row = (((m << 4) + r15) << 3) + (T);                     \
            const int sb  = (r15 + ((T) >> 3)) & 7;                            \
            _Pragma("unroll")                                                  \
            for (int k32 = 0; k32 < 2; ++k32)                                  \
                afr[m][k32] = *(const short8*)&(LA)[(row << 6) +               \
                                   ((((k32 << 2) + hi) ^ sb) << 3)];           \
        }                                                                      \
        _Pragma("unroll")                                                      \
        for (int k32 = 0; k32 < 2; ++k32)                                      \
            _Pragma("unroll")                                                  \
            for (int m = 0; m < 4; ++m)                                        \
                _Pragma("unroll")                                              \
                for (int n = 0; n < 4; ++n)                                    \
                    acc[m][n] = __builtin_amdgcn_mfma_f32_16x16x32_bf16(       \
                        afr[m][k32], BCUR[n][k32], acc[m][n], 0, 0, 0);        \
    }

    load_b8(pk, 0, wid, lane, bc);
    FCISSUE(0, 0) FCISSUE(1, 0) FCISSUE(2, 0) FCISSUE(3, 0) FCISSUE(4, 0)
    FCISSUE(5, 0) FCISSUE(6, 0) FCISSUE(7, 0) FCISSUE(8, 0)
    FCWRITE(0, lsA6[0]) FCWRITE(1, lsA6[0]) FCWRITE(2, lsA6[0]) FCWRITE(3, lsA6[0])
    FCWRITE(4, lsA6[0]) FCWRITE(5, lsA6[0]) FCWRITE(6, lsA6[0]) FCWRITE(7, lsA6[0])
    FCWRITE(8, lsA6[0])
    asm volatile("s_waitcnt lgkmcnt(0)" ::: "memory");
    __builtin_amdgcn_s_barrier();
    __builtin_amdgcn_sched_barrier(0);

    for (int c0 = 0; c0 < 8; ++c0) {
        const unsigned short* La = lsA6[c0 & 1];
        unsigned short* Ln = lsA6[(c0 + 1) & 1];
        const int c0n = c0 + 1;
        const int pf = (c0 < 7);

        FTSTEP(0, La, bc, bn)
        if (pf) { FCISSUE(0, c0n) FCISSUE(1, c0n) }
        FTSTEP(1, La, bn, bc)
        FTSTEP(2, La, bc, bn)
        if (pf) { FCISSUE(2, c0n) FCISSUE(3, c0n) }
        FTSTEP(3, La, bn, bc)
        FTSTEP(4, La, bc, bn)
        if (pf) { FCISSUE(4, c0n) FCISSUE(5, c0n) }
        FTSTEP(5, La, bn, bc)
        FTSTEP(6, La, bc, bn)
        if (pf) { FCISSUE(6, c0n) FCISSUE(7, c0n) }
        FTSTEP(7, La, bn, bc)
        FTSTEP(8, La, bc, bn)
        if (pf) { FCISSUE(8, c0n) FCWRITE(0, Ln) FCWRITE(1, Ln) }
        FTSTEP(9, La, bn, bc)
        FTSTEP(10, La, bc, bn)
        if (pf) { FCWRITE(2, Ln) FCWRITE(3, Ln) }
        FTSTEP(11, La, bn, bc)
        FTSTEP(12, La, bc, bn)
        if (pf) { FCWRITE(4, Ln) FCWRITE(5, Ln) }
        FTSTEP(13, La, bn, bc)
        FTSTEP(14, La, bc, bn)
        if (pf) { FCWRITE(6, Ln) FCWRITE(7, Ln) FCWRITE(8, Ln) }
        FTSTEP(15, La, bn, bc)

        asm volatile("s_waitcnt lgkmcnt(0)" ::: "memory");
        __builtin_amdgcn_s_barrier();
        __builtin_amdgcn_sched_barrier(0);
    }
#undef FTSTEP
#undef FCISSUE
#undef FCWRITE

    float bias4[4], gam4[4], bet4[4];
#pragma unroll
    for (int n = 0; n < 4; ++n) {
        int d = (wid << 6) + 16 * n + r15;
        bias4[n] = bias[d]; gam4[n] = gamma[d]; bet4[n] = beta[d];
    }
    float sum_[4][4], sq_[4][4];
#pragma unroll
    for (int m = 0; m < 4; ++m)
#pragma unroll
        for (int r = 0; r < 4; ++r) { sum_[m][r] = 0.f; sq_[m][r] = 0.f; }
#pragma unroll
    for (int m = 0; m < 4; ++m)
#pragma unroll
        for (int n = 0; n < 4; ++n)
#pragma unroll
            for (int r = 0; r < 4; ++r) {
                float h = acc[m][n][r] + bias4[n];
                float g = 0.5f * h * (1.0f + erff(h * 0.70710678118654752f));
                acc[m][n][r] = g;
                sum_[m][r] += g;
                sq_[m][r]  += g * g;
            }
#pragma unroll
    for (int m = 0; m < 4; ++m)
#pragma unroll
        for (int r = 0; r < 4; ++r) {
            float sv = sum_[m][r], qv = sq_[m][r];
#pragma unroll
            for (int msk = 1; msk < 16; msk <<= 1) {
                sv += __shfl_xor(sv, msk, 64);
                qv += __shfl_xor(qv, msk, 64);
            }
            sum_[m][r] = sv; sq_[m][r] = qv;
        }
    if (r15 == 0) {
#pragma unroll
        for (int m = 0; m < 4; ++m)
#pragma unroll
            for (int r = 0; r < 4; ++r) {
                int row16 = 16 * m + hi * 4 + r;
                redS[wid][row16] = sum_[m][r];
                redQ[wid][row16] = sq_[m][r];
            }
    }
    __syncthreads();
#pragma unroll
    for (int m = 0; m < 4; ++m) {
#pragma unroll
        for (int r = 0; r < 4; ++r) {
            int row16 = 16 * m + hi * 4 + r;
            float sv = 0.f, qv = 0.f;
#pragma unroll
            for (int w = 0; w < 8; ++w) { sv += redS[w][row16]; qv += redQ[w][row16]; }
            float mu  = sv * (1.0f / 512.0f);
            float var = qv * (1.0f / 512.0f) - mu * mu;
            float inv = rsqrtf(var + 1e-5f);
            int win = n0 + row16;
            if (win < NWIN) {
                size_t obase = ((size_t)b * NWIN + win) * D_DIM;
#pragma unroll
                for (int n = 0; n < 4; ++n) {
                    int d = (wid << 6) + 16 * n + r15;
                    out[obase + d] = (acc[m][n][r] - mu) * inv * gam4[n] + bet4[n];
                }
            }
        }
    }
}

// Fallback tier 2 (tiny ws): naive correct kernel.
__global__ void naive_kernel(const float* __restrict__ x, const float* __restrict__ W,
                             const float* __restrict__ bias, const float* __restrict__ gamma,
                             const float* __restrict__ beta, float* __restrict__ out) {
    __shared__ float hrow[D_DIM];
    __shared__ float red[2];
    const int b = blockIdx.x / NWIN, win = blockIdx.x % NWIN;
    const int d = threadIdx.x;
    float a = 0.f;
    for (int t = 0; t < 16; ++t) {
        const float* xr = x + ((size_t)b * S_LEN + 8 * win + t) * D_DIM;
        const float* wr = W + (size_t)t * D_DIM * D_DIM;
        for (int k = 0; k < D_DIM; ++k) a += xr[k] * wr[(size_t)k * D_DIM + d];
    }
    a += bias[d];
    a = 0.5f * a * (1.0f + erff(a * 0.70710678118654752f));
    hrow[d] = a;
    __syncthreads();
    if (d == 0) {
        float s = 0.f, q = 0.f;
        for (int k = 0; k < D_DIM; ++k) { s += hrow[k]; q += hrow[k] * hrow[k]; }
        float mu = s / D_DIM;
        red[0] = mu; red[1] = rsqrtf(q / D_DIM - mu * mu + 1e-5f);
    }
    __syncthreads();
    out[((size_t)b * NWIN + win) * D_DIM + d] = (a - red[0]) * red[1] * gamma[d] + beta[d];
}

extern "C" void kernel_launch(void* const* d_in, const int* in_sizes, int n_in,
                              void* d_out, int out_size, void* d_ws, size_t ws_size,
                              hipStream_t stream) {
    const float* x     = (const float*)d_in[0];
    const float* W     = (const float*)d_in[1];
    const float* bias  = (const float*)d_in[2];
    const float* gamma = (const float*)d_in[3];
    const float* beta  = (const float*)d_in[4];
    float* out = (float*)d_out;

    const size_t pk_bytes = (size_t)KDIM * D_DIM * sizeof(unsigned short);   // 8 MB
    const size_t ph_bytes = 2 * PH_ELEMS * sizeof(float);                    // 67 MB

    if (ws_size >= pk_bytes + ph_bytes) {
        short8* pk = (short8*)d_ws;
        float* ph = (float*)((char*)d_ws + pk_bytes);
        wpack2_kernel<<<1024, 256, 0, stream>>>(W, pk);
        gemm6_kernel<<<512, 512, 0, stream>>>(x, pk, ph);
        ln2_kernel<<<1024, 256, 0, stream>>>(ph, bias, gamma, beta, out, 32 * NWIN);
    } else if (ws_size >= pk_bytes) {
        short8* pk = (short8*)d_ws;
        wpack_c0_kernel<<<1024, 256, 0, stream>>>(W, pk);
        fusedR6_kernel<<<256, 512, 0, stream>>>(x, pk, bias, gamma, beta, out);
    } else {
        naive_kernel<<<32 * NWIN, D_DIM, 0, stream>>>(x, W, bias, gamma, beta, out);
    }
}